// Round 3
// baseline (4595.995 us; speedup 1.0000x reference)
//
#include <hip/hip_runtime.h>
#include <hip/hip_bf16.h>
#include <hip/hip_cooperative_groups.h>

namespace cg = cooperative_groups;

#define T_STEPS 100
#define NG 4096
#define NP 512

typedef __bf16 bf16x8 __attribute__((ext_vector_type(8)));
typedef float f32x4 __attribute__((ext_vector_type(4)));

__device__ __forceinline__ f32x4 mfma_bf16(bf16x8 a, bf16x8 b, f32x4 c) {
  return __builtin_amdgcn_mfma_f32_16x16x32_bf16(a, b, c, 0, 0, 0);
}

// ---------------- f32 -> bf16 conversion, 8 elems/thread ----------------
__global__ __launch_bounds__(256) void cvt_bf16_kernel(const float* __restrict__ in,
                                                       __hip_bfloat16* __restrict__ out,
                                                       int n8) {
  int i = blockIdx.x * 256 + threadIdx.x;
  if (i >= n8) return;
  const float4* p = reinterpret_cast<const float4*>(in) + (size_t)i * 2;
  float4 f0 = p[0], f1 = p[1];
  union { __hip_bfloat16 h[8]; uint4 u; } z;
  z.h[0] = __float2bfloat16(f0.x); z.h[1] = __float2bfloat16(f0.y);
  z.h[2] = __float2bfloat16(f0.z); z.h[3] = __float2bfloat16(f0.w);
  z.h[4] = __float2bfloat16(f1.x); z.h[5] = __float2bfloat16(f1.y);
  z.h[6] = __float2bfloat16(f1.z); z.h[7] = __float2bfloat16(f1.w);
  *(reinterpret_cast<uint4*>(out) + i) = z.u;
}

// ---------------- encoder: h0 = p0 @ W_enc^T  -> bf16 -------------------
__global__ __launch_bounds__(256) void encoder_kernel(const float* __restrict__ p0,
                                                      const float* __restrict__ Wenc,
                                                      __hip_bfloat16* __restrict__ h0) {
  __shared__ float sp[64 * 129];
  const int tid = threadIdx.x;
  const int nb = blockIdx.x * 16;
  const int b = tid & 63;
  const int jg = tid >> 6;
  float acc[4] = {0.f, 0.f, 0.f, 0.f};
  for (int kc = 0; kc < NP; kc += 128) {
    __syncthreads();
    #pragma unroll
    for (int i = 0; i < 32; ++i) {
      int e = tid + i * 256;
      int bb = e >> 7, kk = e & 127;
      sp[bb * 129 + kk] = p0[bb * NP + kc + kk];
    }
    __syncthreads();
    for (int kk = 0; kk < 128; ++kk) {
      float pv = sp[b * 129 + kk];
      #pragma unroll
      for (int jj = 0; jj < 4; ++jj)
        acc[jj] += pv * Wenc[(size_t)(nb + jg * 4 + jj) * NP + kc + kk];
    }
  }
  #pragma unroll
  for (int jj = 0; jj < 4; ++jj)
    h0[(size_t)b * NG + nb + jg * 4 + jj] = __float2bfloat16(acc[jj]);
}

// ---------------- cooperative RNN: all 100 steps, Wh slice in LDS -------
// grid = 256 blocks x 512 thr (8 waves). Block owns n-cols [16*bid, +16).
// LDS: Wh slice [16 rows][4096 k] bf16, XOR-swizzled: 16B chunk index within
// a row is XORed with (row&7)  (byte ^= (row&7)<<4)  -> breaks the 16-way
// bank conflict of the 8KB row stride.
// Read side: the ENTIRE XOR is applied to the LDS read address (bits 4-5 in
// the per-lane base via kg^(row&3); bit 6 folded into the four slot base
// pointers via slot*64 ^ ((row&4)<<4)). Every lane reads its correct logical
// k-chunk -- NO operand-side compensation (a per-lane A-column swap is
// invalid across lanes; that was round-2's bug).
// Wave (ms = w&3, kh = w>>2): m-strip of 16 b's, k-half of 2048.
// vv / z_prev state lives in kh0 thread registers (4 cells each).
__global__ __launch_bounds__(512, 2) void rnn_all_kernel(
    const __hip_bfloat16* __restrict__ h0,
    const float* __restrict__ Wh_f32,
    const float* __restrict__ v, const float* __restrict__ Win,
    __hip_bfloat16* __restrict__ gs) {
  extern __shared__ char smem[];                  // 131072 (Wh) + 4096 (red)
  float* red = (float*)(smem + 131072);

  const int tid = threadIdx.x;
  const int n0 = blockIdx.x * 16;

  // ---- prologue: load 16 rows of Wh (f32), cvt bf16, store swizzled ----
  #pragma unroll
  for (int i = 0; i < 16; ++i) {
    int chunk = tid + i * 512;          // 8192 chunks of 8 elems
    int row = chunk >> 9;               // 512 chunks per row
    int c8 = chunk & 511;
    const float* src = Wh_f32 + (size_t)(n0 + row) * NG + c8 * 8;
    float4 f0 = *(const float4*)src;
    float4 f1 = *(const float4*)(src + 4);
    union { __hip_bfloat16 h[8]; uint4 u; } z;
    z.h[0] = __float2bfloat16(f0.x); z.h[1] = __float2bfloat16(f0.y);
    z.h[2] = __float2bfloat16(f0.z); z.h[3] = __float2bfloat16(f0.w);
    z.h[4] = __float2bfloat16(f1.x); z.h[5] = __float2bfloat16(f1.y);
    z.h[6] = __float2bfloat16(f1.z); z.h[7] = __float2bfloat16(f1.w);
    int dst = row * 8192 + ((c8 * 16) ^ ((row & 7) << 4));
    *(uint4*)(smem + dst) = z.u;
  }
  __syncthreads();

  const int lane = tid & 63;
  const int w = tid >> 6;
  const int ms = w & 3;    // m strip (16 b rows)
  const int kh = w >> 2;   // k half
  const int row = lane & 15;   // = n within block (B) and b within strip (A)
  const int kg = lane >> 4;    // k-group 0..3
  const int k0 = kh * 2048 + kg * 8;
  // per-lane swizzled LDS base: XOR bits 4-5 (kg ^ row&3); bit 6 folded into
  // the four slot pointers below. Base bit 6 is 0, so '+' is exact.
  char* ldsB = smem + row * 8192 + kh * 4096 + ((kg * 16) ^ ((row & 3) << 4));
  const int x6 = (row & 4) << 4;  // 64 if row has bit 2
  char* ldsB0 = ldsB + (0   ^ x6);
  char* ldsB1 = ldsB + (64  ^ x6);
  char* ldsB2 = ldsB + (128 ^ x6);
  char* ldsB3 = ldsB + (192 ^ x6);
  const int n = n0 + row;
  const int row_a = ms * 16 + row;

  float wi0 = 0.f, wi1 = 0.f;
  if (kh == 0) { wi0 = Win[n * 2]; wi1 = Win[n * 2 + 1]; }
  float vvr[4] = {0.f, 0.f, 0.f, 0.f};
  float zpr[4] = {0.f, 0.f, 0.f, 0.f};

  cg::grid_group grid = cg::this_grid();

  for (int t = 0; t < T_STEPS; ++t) {
    const __hip_bfloat16* Ab;
    size_t stA;
    if (t == 0) { Ab = h0; stA = NG; }
    else        { Ab = gs + (size_t)(t - 1) * NG; stA = (size_t)T_STEPS * NG; }
    const __hip_bfloat16* pab = Ab + (size_t)row_a * stA + k0;

    f32x4 acc0{}, acc1{}, acc2{}, acc3{};
    #pragma unroll
    for (int c = 0; c < 16; ++c) {
      bf16x8 A0 = *(const bf16x8*)(pab + c * 128);
      bf16x8 B0 = *(const bf16x8*)(ldsB0 + c * 256);
      acc0 = mfma_bf16(A0, B0, acc0);
      bf16x8 A1 = *(const bf16x8*)(pab + c * 128 + 32);
      bf16x8 B1 = *(const bf16x8*)(ldsB1 + c * 256);
      acc1 = mfma_bf16(A1, B1, acc1);
      bf16x8 A2 = *(const bf16x8*)(pab + c * 128 + 64);
      bf16x8 B2 = *(const bf16x8*)(ldsB2 + c * 256);
      acc2 = mfma_bf16(A2, B2, acc2);
      bf16x8 A3 = *(const bf16x8*)(pab + c * 128 + 96);
      bf16x8 B3 = *(const bf16x8*)(ldsB3 + c * 256);
      acc3 = mfma_bf16(A3, B3, acc3);
    }
    acc0 += acc1; acc2 += acc3; acc0 += acc2;

    if (kh == 1) {
      #pragma unroll
      for (int j = 0; j < 4; ++j) red[(ms * 64 + lane) * 4 + j] = acc0[j];
    }
    __syncthreads();
    if (kh == 0) {
      #pragma unroll
      for (int j = 0; j < 4; ++j) {
        int b = ms * 16 + kg * 4 + j;
        float z = acc0[j] + red[(ms * 64 + lane) * 4 + j];
        float2 vt = *(const float2*)(v + (b * T_STEPS + t) * 2);
        z += vt.x * wi0 + vt.y * wi1;
        z -= 0.5f * vvr[j];                          // z uses OLD vv
        float vvn = vvr[j] + 0.1f * (zpr[j] - vvr[j]);  // vv update uses z_{t-1}
        vvr[j] = fmaxf(vvn, 0.f);
        zpr[j] = z;                                  // pre-relu z
        gs[(size_t)(b * T_STEPS + t) * NG + n] = __float2bfloat16(fmaxf(z, 0.f));
      }
    }
    grid.sync();
  }
}

// ---------------- decoder: logits = gs @ W_dec^T ------------------------
__global__ __launch_bounds__(256) void decoder_kernel(const __hip_bfloat16* __restrict__ gs,
                                                      const __hip_bfloat16* __restrict__ Wd,
                                                      float* __restrict__ out) {
  const int lane = threadIdx.x & 63;
  const int w = threadIdx.x >> 6;
  const int m0 = blockIdx.x * 64 + w * 16;
  const int n0 = blockIdx.y * 64;
  const int k0 = (lane >> 4) * 8;
  const __hip_bfloat16* pa = gs + (size_t)(m0 + (lane & 15)) * NG + k0;
  const __hip_bfloat16* pb = Wd + (size_t)(n0 + (lane & 15)) * NG + k0;
  f32x4 a0{}, a1{}, a2{}, a3{};
  for (int c = 0; c < NG / 32; ++c) {
    bf16x8 av = *reinterpret_cast<const bf16x8*>(pa + c * 32);
    bf16x8 b0 = *reinterpret_cast<const bf16x8*>(pb + c * 32);
    bf16x8 b1 = *reinterpret_cast<const bf16x8*>(pb + (size_t)16 * NG + c * 32);
    bf16x8 b2 = *reinterpret_cast<const bf16x8*>(pb + (size_t)32 * NG + c * 32);
    bf16x8 b3 = *reinterpret_cast<const bf16x8*>(pb + (size_t)48 * NG + c * 32);
    a0 = mfma_bf16(av, b0, a0);
    a1 = mfma_bf16(av, b1, a1);
    a2 = mfma_bf16(av, b2, a2);
    a3 = mfma_bf16(av, b3, a3);
  }
  const int col = lane & 15, r4 = (lane >> 4) * 4;
  #pragma unroll
  for (int j = 0; j < 4; ++j) {
    float* po = out + (size_t)(m0 + r4 + j) * NP + n0;
    po[col] = a0[j];
    po[col + 16] = a1[j];
    po[col + 32] = a2[j];
    po[col + 48] = a3[j];
  }
}

// ---------------- log_softmax over rows of 512 (in place) ---------------
__global__ __launch_bounds__(256) void logsoftmax_kernel(float* __restrict__ out) {
  float* row = out + (size_t)blockIdx.x * NP;
  const int tid = threadIdx.x;
  const int lane = tid & 63, wid = tid >> 6;
  float x0 = row[tid], x1 = row[tid + 256];
  float m = fmaxf(x0, x1);
  #pragma unroll
  for (int off = 32; off >= 1; off >>= 1) m = fmaxf(m, __shfl_xor(m, off));
  __shared__ float sred[8];
  if (lane == 0) sred[wid] = m;
  __syncthreads();
  m = fmaxf(fmaxf(sred[0], sred[1]), fmaxf(sred[2], sred[3]));
  float e = __expf(x0 - m) + __expf(x1 - m);
  #pragma unroll
  for (int off = 32; off >= 1; off >>= 1) e += __shfl_xor(e, off);
  if (lane == 0) sred[4 + wid] = e;
  __syncthreads();
  float lse = m + __logf(sred[4] + sred[5] + sred[6] + sred[7]);
  row[tid] = x0 - lse;
  row[tid + 256] = x1 - lse;
}

extern "C" void kernel_launch(void* const* d_in, const int* in_sizes, int n_in,
                              void* d_out, int out_size, void* d_ws, size_t ws_size,
                              hipStream_t stream) {
  const float* v    = (const float*)d_in[0];  // [64,100,2]
  const float* p0   = (const float*)d_in[1];  // [64,512]
  const float* Wenc = (const float*)d_in[2];  // [4096,512]
  const float* Win  = (const float*)d_in[3];  // [4096,2]
  const float* Wh   = (const float*)d_in[4];  // [4096,4096]
  const float* Wdec = (const float*)d_in[5];  // [512,4096]
  float* out = (float*)d_out;                 // [64,100,512]

  char* ws = (char*)d_ws;
  __hip_bfloat16* Wdec_bf = (__hip_bfloat16*)(ws);              //  4,194,304 B
  __hip_bfloat16* h0_bf   = (__hip_bfloat16*)(ws + 4194304);    //    524,288 B
  __hip_bfloat16* gs      = (__hip_bfloat16*)(ws + 8388608);    // 52,428,800 B

  cvt_bf16_kernel<<<1024, 256, 0, stream>>>(Wdec, Wdec_bf, 262144);
  encoder_kernel<<<256, 256, 0, stream>>>(p0, Wenc, h0_bf);

  const unsigned lds_bytes = 131072 + 4096;
  hipFuncSetAttribute((const void*)rnn_all_kernel,
                      hipFuncAttributeMaxDynamicSharedMemorySize, (int)lds_bytes);
  void* args[] = {(void*)&h0_bf, (void*)&Wh, (void*)&v, (void*)&Win, (void*)&gs};
  hipLaunchCooperativeKernel((const void*)rnn_all_kernel, dim3(256), dim3(512),
                             args, lds_bytes, stream);

  decoder_kernel<<<dim3(100, 8), 256, 0, stream>>>(gs, Wdec_bf, out);
  logsoftmax_kernel<<<6400, 256, 0, stream>>>(out);
}

// Round 4
// 2407.919 us; speedup vs baseline: 1.9087x; 1.9087x over previous
//
#include <hip/hip_runtime.h>
#include <hip/hip_bf16.h>

#define T_STEPS 100
#define NG 4096
#define NP 512

typedef __bf16 bf16x8 __attribute__((ext_vector_type(8)));
typedef float f32x4 __attribute__((ext_vector_type(4)));

__device__ __forceinline__ f32x4 mfma_bf16(bf16x8 a, bf16x8 b, f32x4 c) {
  return __builtin_amdgcn_mfma_f32_16x16x32_bf16(a, b, c, 0, 0, 0);
}

// ---------------- f32 -> bf16 conversion, 8 elems/thread ----------------
__global__ __launch_bounds__(256) void cvt_bf16_kernel(const float* __restrict__ in,
                                                       __hip_bfloat16* __restrict__ out,
                                                       int n8) {
  int i = blockIdx.x * 256 + threadIdx.x;
  if (i >= n8) return;
  const float4* p = reinterpret_cast<const float4*>(in) + (size_t)i * 2;
  float4 f0 = p[0], f1 = p[1];
  union { __hip_bfloat16 h[8]; uint4 u; } z;
  z.h[0] = __float2bfloat16(f0.x); z.h[1] = __float2bfloat16(f0.y);
  z.h[2] = __float2bfloat16(f0.z); z.h[3] = __float2bfloat16(f0.w);
  z.h[4] = __float2bfloat16(f1.x); z.h[5] = __float2bfloat16(f1.y);
  z.h[6] = __float2bfloat16(f1.z); z.h[7] = __float2bfloat16(f1.w);
  *(reinterpret_cast<uint4*>(out) + i) = z.u;
}

// ---------------- encoder: h0 = p0 @ W_enc^T  -> bf16 -------------------
__global__ __launch_bounds__(256) void encoder_kernel(const float* __restrict__ p0,
                                                      const float* __restrict__ Wenc,
                                                      __hip_bfloat16* __restrict__ h0) {
  __shared__ float sp[64 * 129];
  const int tid = threadIdx.x;
  const int nb = blockIdx.x * 16;
  const int b = tid & 63;
  const int jg = tid >> 6;
  float acc[4] = {0.f, 0.f, 0.f, 0.f};
  for (int kc = 0; kc < NP; kc += 128) {
    __syncthreads();
    #pragma unroll
    for (int i = 0; i < 32; ++i) {
      int e = tid + i * 256;
      int bb = e >> 7, kk = e & 127;
      sp[bb * 129 + kk] = p0[bb * NP + kc + kk];
    }
    __syncthreads();
    for (int kk = 0; kk < 128; ++kk) {
      float pv = sp[b * 129 + kk];
      #pragma unroll
      for (int jj = 0; jj < 4; ++jj)
        acc[jj] += pv * Wenc[(size_t)(nb + jg * 4 + jj) * NP + kc + kk];
    }
  }
  #pragma unroll
  for (int jj = 0; jj < 4; ++jj)
    h0[(size_t)b * NG + nb + jg * 4 + jj] = __float2bfloat16(acc[jj]);
}

// ---------------- RNN GEMM partial: zpart[kq] = A_kslice @ Wh_kslice^T --
// grid (64 ng, 8 kq), block 256 thr = 4 waves (ms = w>>1 in {0,1}: 32 b-rows;
// ns = w&1: 32 n-cols). Wave tile 32b x 32n x 512k, 2x2 frags of 16x16x32.
// No LDS; A-frags shared by ns-waves and B-frags by ms-waves hit in L1.
// Fully unrolled k-loop with explicit 1-deep register double-buffer.
__global__ __launch_bounds__(256, 2) void rnn_gemm_kernel(
    const __hip_bfloat16* __restrict__ A, int strideA,
    const __hip_bfloat16* __restrict__ Wh,
    float* __restrict__ zpart) {
  const int lane = threadIdx.x & 63;
  const int w = threadIdx.x >> 6;
  const int ms = w >> 1, ns = w & 1;
  const int ng = blockIdx.x, kq = blockIdx.y;
  const int r = lane & 15;       // row within 16-frag (b for A, n for B)
  const int kg = lane >> 4;      // k-group
  const int kbase = kq * 512 + kg * 8;
  const int n0 = ng * 64 + ns * 32;

  const __hip_bfloat16* pA0 = A + (size_t)(ms * 32 + r) * strideA + kbase;
  const __hip_bfloat16* pA1 = pA0 + (size_t)16 * strideA;
  const __hip_bfloat16* pB0 = Wh + (size_t)(n0 + r) * NG + kbase;
  const __hip_bfloat16* pB1 = pB0 + (size_t)16 * NG;

  f32x4 acc00{}, acc01{}, acc10{}, acc11{};
  bf16x8 cA0 = *(const bf16x8*)(pA0);
  bf16x8 cA1 = *(const bf16x8*)(pA1);
  bf16x8 cB0 = *(const bf16x8*)(pB0);
  bf16x8 cB1 = *(const bf16x8*)(pB1);
  #pragma unroll
  for (int it = 0; it < 16; ++it) {
    bf16x8 nA0, nA1, nB0, nB1;
    if (it < 15) {
      nA0 = *(const bf16x8*)(pA0 + (it + 1) * 32);
      nA1 = *(const bf16x8*)(pA1 + (it + 1) * 32);
      nB0 = *(const bf16x8*)(pB0 + (it + 1) * 32);
      nB1 = *(const bf16x8*)(pB1 + (it + 1) * 32);
    }
    acc00 = mfma_bf16(cA0, cB0, acc00);
    acc01 = mfma_bf16(cA0, cB1, acc01);
    acc10 = mfma_bf16(cA1, cB0, acc10);
    acc11 = mfma_bf16(cA1, cB1, acc11);
    if (it < 15) { cA0 = nA0; cA1 = nA1; cB0 = nB0; cB1 = nB1; }
  }

  // store: C row b = ms*32 + fi*16 + (lane>>4)*4 + j; col n = n0 + fj*16 + r
  float* zb = zpart + ((size_t)(kq * 64 + ms * 32 + kg * 4) << 12) + n0 + r;
  #pragma unroll
  for (int j = 0; j < 4; ++j) {
    zb[(size_t)j * NG]                    = acc00[j];
    zb[(size_t)j * NG + 16]               = acc01[j];
    zb[(size_t)(16 + j) * NG]             = acc10[j];
    zb[(size_t)(16 + j) * NG + 16]        = acc11[j];
  }
}

// ---------------- RNN epilogue: sum partials + recurrence + relu --------
// grid 256 x 256 thr; thread handles 4 consecutive n of one b.
__global__ __launch_bounds__(256) void rnn_epi_kernel(
    const float* __restrict__ zpart,
    const float* __restrict__ v, const float* __restrict__ Win,
    float* __restrict__ vv, float* __restrict__ zp,
    __hip_bfloat16* __restrict__ gs, int t) {
  const int g = blockIdx.x * 256 + threadIdx.x;   // 0..65535
  const int b = g >> 10;
  const int n = (g & 1023) * 4;
  f32x4 s{};
  #pragma unroll
  for (int kq = 0; kq < 8; ++kq)
    s += *(const f32x4*)(zpart + ((size_t)(kq * 64 + b) << 12) + n);
  float2 vt = *(const float2*)(v + (b * T_STEPS + t) * 2);
  float4 wA = *(const float4*)(Win + 2 * n);
  float4 wB = *(const float4*)(Win + 2 * n + 4);
  f32x4 z;
  z[0] = s[0] + vt.x * wA.x + vt.y * wA.y;
  z[1] = s[1] + vt.x * wA.z + vt.y * wA.w;
  z[2] = s[2] + vt.x * wB.x + vt.y * wB.y;
  z[3] = s[3] + vt.x * wB.z + vt.y * wB.w;
  f32x4 vvo = *(const f32x4*)(vv + (size_t)b * NG + n);
  f32x4 zpo = *(const f32x4*)(zp + (size_t)b * NG + n);
  union { __hip_bfloat16 h[4]; ushort2 u2[2]; uint2 u; } o;
  f32x4 vvn;
  #pragma unroll
  for (int j = 0; j < 4; ++j) {
    z[j] -= 0.5f * vvo[j];                       // z uses OLD vv
    vvn[j] = fmaxf(vvo[j] + 0.1f * (zpo[j] - vvo[j]), 0.f);
    o.h[j] = __float2bfloat16(fmaxf(z[j], 0.f));
  }
  *(f32x4*)(vv + (size_t)b * NG + n) = vvn;
  *(f32x4*)(zp + (size_t)b * NG + n) = z;        // pre-relu z
  *(uint2*)(gs + (size_t)(b * T_STEPS + t) * NG + n) = o.u;
}

// ---------------- decoder: logits = gs @ W_dec^T ------------------------
// grid (200, 8), block 256 = 4 waves (ms in {0,1}: 16m, nh in {0,1}: 32n).
// Explicit 1-deep prefetch pipeline; ~25 waves/CU occupancy.
__global__ __launch_bounds__(256, 4) void decoder_kernel(
    const __hip_bfloat16* __restrict__ gs,
    const __hip_bfloat16* __restrict__ Wd,
    float* __restrict__ out) {
  const int lane = threadIdx.x & 63;
  const int w = threadIdx.x >> 6;
  const int ms = w >> 1, nh = w & 1;
  const int m0 = blockIdx.x * 32 + ms * 16;
  const int n0 = blockIdx.y * 64 + nh * 32;
  const int r = lane & 15;
  const int kg = lane >> 4;
  const __hip_bfloat16* pa = gs + (size_t)(m0 + r) * NG + kg * 8;
  const __hip_bfloat16* pb0 = Wd + (size_t)(n0 + r) * NG + kg * 8;
  const __hip_bfloat16* pb1 = pb0 + (size_t)16 * NG;
  f32x4 a0{}, a1{};
  bf16x8 ca = *(const bf16x8*)(pa);
  bf16x8 cb0 = *(const bf16x8*)(pb0);
  bf16x8 cb1 = *(const bf16x8*)(pb1);
  #pragma unroll 4
  for (int c = 0; c < 127; ++c) {
    bf16x8 na = *(const bf16x8*)(pa + (c + 1) * 32);
    bf16x8 nb0 = *(const bf16x8*)(pb0 + (c + 1) * 32);
    bf16x8 nb1 = *(const bf16x8*)(pb1 + (c + 1) * 32);
    a0 = mfma_bf16(ca, cb0, a0);
    a1 = mfma_bf16(ca, cb1, a1);
    ca = na; cb0 = nb0; cb1 = nb1;
  }
  a0 = mfma_bf16(ca, cb0, a0);
  a1 = mfma_bf16(ca, cb1, a1);
  #pragma unroll
  for (int j = 0; j < 4; ++j) {
    float* po = out + (size_t)(m0 + kg * 4 + j) * NP + n0;
    po[r] = a0[j];
    po[r + 16] = a1[j];
  }
}

// ---------------- log_softmax over rows of 512 (in place) ---------------
__global__ __launch_bounds__(256) void logsoftmax_kernel(float* __restrict__ out) {
  float* row = out + (size_t)blockIdx.x * NP;
  const int tid = threadIdx.x;
  const int lane = tid & 63, wid = tid >> 6;
  float x0 = row[tid], x1 = row[tid + 256];
  float m = fmaxf(x0, x1);
  #pragma unroll
  for (int off = 32; off >= 1; off >>= 1) m = fmaxf(m, __shfl_xor(m, off));
  __shared__ float sred[8];
  if (lane == 0) sred[wid] = m;
  __syncthreads();
  m = fmaxf(fmaxf(sred[0], sred[1]), fmaxf(sred[2], sred[3]));
  float e = __expf(x0 - m) + __expf(x1 - m);
  #pragma unroll
  for (int off = 32; off >= 1; off >>= 1) e += __shfl_xor(e, off);
  if (lane == 0) sred[4 + wid] = e;
  __syncthreads();
  float lse = m + __logf(sred[4] + sred[5] + sred[6] + sred[7]);
  row[tid] = x0 - lse;
  row[tid + 256] = x1 - lse;
}

extern "C" void kernel_launch(void* const* d_in, const int* in_sizes, int n_in,
                              void* d_out, int out_size, void* d_ws, size_t ws_size,
                              hipStream_t stream) {
  const float* v    = (const float*)d_in[0];  // [64,100,2]
  const float* p0   = (const float*)d_in[1];  // [64,512]
  const float* Wenc = (const float*)d_in[2];  // [4096,512]
  const float* Win  = (const float*)d_in[3];  // [4096,2]
  const float* Wh   = (const float*)d_in[4];  // [4096,4096]
  const float* Wdec = (const float*)d_in[5];  // [512,4096]
  float* out = (float*)d_out;                 // [64,100,512]

  char* ws = (char*)d_ws;
  __hip_bfloat16* gs      = (__hip_bfloat16*)(ws);               // 52,428,800
  __hip_bfloat16* Wh_bf   = (__hip_bfloat16*)(ws + 52428800);    // 33,554,432
  float*          zpart   = (float*)(ws + 85983232);             //  8,388,608
  __hip_bfloat16* Wdec_bf = (__hip_bfloat16*)(ws + 85983232);    // aliases zpart (used after RNN)
  float*          vv      = (float*)(ws + 94371840);             //  1,048,576
  float*          zp      = (float*)(ws + 95420416);             //  1,048,576
  __hip_bfloat16* h0_bf   = (__hip_bfloat16*)(ws + 96468992);    //    524,288
  // total 96,993,280 B

  hipMemsetAsync(vv, 0, 2 * 1048576, stream);  // vv + zp (contiguous)
  cvt_bf16_kernel<<<8192, 256, 0, stream>>>(Wh, Wh_bf, 2097152);
  encoder_kernel<<<256, 256, 0, stream>>>(p0, Wenc, h0_bf);

  for (int t = 0; t < T_STEPS; ++t) {
    const __hip_bfloat16* A = (t == 0) ? h0_bf : (gs + (size_t)(t - 1) * NG);
    int sA = (t == 0) ? NG : T_STEPS * NG;
    rnn_gemm_kernel<<<dim3(64, 8), 256, 0, stream>>>(A, sA, Wh_bf, zpart);
    rnn_epi_kernel<<<256, 256, 0, stream>>>(zpart, v, Win, vv, zp, gs, t);
  }

  cvt_bf16_kernel<<<1024, 256, 0, stream>>>(Wdec, Wdec_bf, 262144);  // after RNN (aliases zpart)
  decoder_kernel<<<dim3(200, 8), 256, 0, stream>>>(gs, Wdec_bf, out);
  logsoftmax_kernel<<<6400, 256, 0, stream>>>(out);
}